// Round 12
// baseline (142.629 us; speedup 1.0000x reference)
//
#include <hip/hip_runtime.h>
#include <math.h>

typedef _Float16 f16;
typedef __attribute__((ext_vector_type(8))) _Float16 f16x8;
typedef __attribute__((ext_vector_type(4))) _Float16 f16x4;
typedef __attribute__((ext_vector_type(4))) float f32x4;
typedef __attribute__((ext_vector_type(16))) float f32x16;

#define MFMA16(a, b, c) __builtin_amdgcn_mfma_f32_16x16x32_f16((a), (b), (c), 0, 0, 0)
#define MFMA32(a, b, c) __builtin_amdgcn_mfma_f32_32x32x16_f16((a), (b), (c), 0, 0, 0)

__device__ __forceinline__ void gld16(const f16* g, f16* l) {
  __builtin_amdgcn_global_load_lds(
      (const __attribute__((address_space(1))) unsigned int*)g,
      (__attribute__((address_space(3))) unsigned int*)l, 16, 0, 0);
}

__device__ __forceinline__ f16x8 pack8(const float* src) {
  float4 f0 = *(const float4*)src;
  float4 f1 = *(const float4*)(src + 4);
  f16x8 v;
  v[0] = (f16)f0.x; v[1] = (f16)f0.y; v[2] = (f16)f0.z; v[3] = (f16)f0.w;
  v[4] = (f16)f1.x; v[5] = (f16)f1.y; v[6] = (f16)f1.z; v[7] = (f16)f1.w;
  return v;
}

// ---------------- prep: eww = exp(wbias) in MFMA-fragment order ----------------
// eww[((mblk*256 + c)*64 + lane)*8 + e] = exp(wb[mblk*32 + (lane&31)][c*16 + (lane>>5)*8 + e])
// grid 2048 = 128 mblk x 16 cg; block stages wb 32x256 f32 in LDS (coalesced),
// emits 16 fragment units (1 KB each) coalesced. bid<128 also cast QKV weights;
// bid==128 builds wpf (wp in fragment order).
__global__ __launch_bounds__(256) void prep_eww(const float* __restrict__ wb,
                                                f16* __restrict__ eww,
                                                const float* __restrict__ wq,
                                                const float* __restrict__ wk,
                                                const float* __restrict__ wv,
                                                const float* __restrict__ wp,
                                                f16* __restrict__ wqkvb,
                                                f16* __restrict__ wpf) {
  __shared__ float sL[32 * 261];
  const int tid = threadIdx.x;
  const int bid = blockIdx.x;
  const int mblk = bid >> 4;
  const int cg = bid & 15;
#pragma unroll
  for (int u = 0; u < 8; ++u) {
    int d = u * 256 + tid;
    int row = d >> 6, c4 = d & 63;
    float4 v = *(const float4*)(wb + (size_t)(mblk * 32 + row) * 4096 + cg * 256 + c4 * 4);
    float* p = &sL[row * 261 + c4 * 4];
    p[0] = v.x; p[1] = v.y; p[2] = v.z; p[3] = v.w;
  }
  __syncthreads();
  const int wv_ = tid >> 6, lane = tid & 63;
  const int row = lane & 31, kh = (lane >> 5) * 8;
#pragma unroll
  for (int q = 0; q < 4; ++q) {
    const int cl = wv_ * 4 + q;
    const float* src = &sL[row * 261 + cl * 16 + kh];
    f16x8 o;
#pragma unroll
    for (int e = 0; e < 8; ++e) o[e] = (f16)expf(src[e]);
    *(f16x8*)(eww + ((((size_t)mblk * 256) + cg * 16 + cl) * 64 + lane) * 8) = o;
  }
  if (bid < 128) {
    int i = bid * 256 + tid;
    wqkvb[i] = (f16)wk[i];
    wqkvb[32768 + i] = (f16)wv[i];
    wqkvb[65536 + i] = (f16)wq[i];
  }
  if (bid == 128) {
#pragma unroll
    for (int u = 0; u < 16; ++u) {
      int d = u * 256 + tid;  // 0..4095: (dcb*4 + c)*64 + l
      int dcb = d >> 8, c = (d >> 6) & 3, l = d & 63;
      const float* src = wp + (size_t)(dcb * 32 + (l & 31)) * 64 + c * 16 + (l >> 5) * 8;
      f16x8 o;
#pragma unroll
      for (int e = 0; e < 8; ++e) o[e] = (f16)src[e];
      *(f16x8*)(wpf + ((size_t)d << 3)) = o;
    }
  }
}

// ---------------- k1_qkv: sigQ[m][h]; XT2 = {eK*V, eK} in fragment order ----------
// XT2[(((b*4+cb)*256 + c)*64 + lane)*8 + e]:
//   cb 0,1 = eKV rows h = cb*32+(lane&31); cb 2,3 = eK rows h = (cb-2)*32+(lane&31);
//   t = c*16 + (lane>>5)*8 + e. Emitted via LDS transpose, coalesced 1 KB stores.
__global__ __launch_bounds__(256) void k1_qkv(const float* __restrict__ x,
                                              const f16* __restrict__ wqkvb,
                                              const float* __restrict__ bq,
                                              const float* __restrict__ bk,
                                              const float* __restrict__ bv,
                                              f16* __restrict__ sigQ,
                                              f16* __restrict__ XT2) {
  __shared__ alignas(16) f16 sW[192 * 64];
  __shared__ alignas(16) f16 sX[64 * 64];
  const int tid = threadIdx.x;
  const int wave = tid >> 6, lane = tid & 63;
  const int m0 = blockIdx.x * 64;
  const int l15 = lane & 15;

  f32x4 accQ[4], accK[4], accV[4];
#pragma unroll
  for (int j = 0; j < 4; ++j) {
    accQ[j] = (f32x4){0.f, 0.f, 0.f, 0.f};
    accK[j] = (f32x4){0.f, 0.f, 0.f, 0.f};
    accV[j] = (f32x4){0.f, 0.f, 0.f, 0.f};
  }

  const int sc8 = tid & 7;
  const int wr8 = (tid >> 3) & 7;
  const int wcol = (sc8 ^ wr8) * 8;

  for (int ks = 0; ks < 512; ks += 64) {
#pragma unroll
    for (int q = 0; q < 6; ++q) {
      int r = q * 32 + (tid >> 3);
      gld16(wqkvb + (size_t)r * 512 + ks + wcol, &sW[r * 64 + sc8 * 8]);
    }
#pragma unroll
    for (int u = 0; u < 2; ++u) {
      int un = tid + u * 256;
      int r = un >> 3, c8 = un & 7;
      *(f16x8*)&sX[r * 64 + ((c8 ^ (r & 7)) * 8)] =
          pack8(x + (size_t)(m0 + r) * 512 + ks + c8 * 8);
    }
    __syncthreads();
#pragma unroll
    for (int kk = 0; kk < 2; ++kk) {
      const int c = kk * 4 + (lane >> 4);
      const int rK = wave * 16 + l15;
      const int rV = 64 + rK;
      f16x8 aK = *(const f16x8*)&sW[rK * 64 + ((c ^ (rK & 7)) * 8)];
      f16x8 aV = *(const f16x8*)&sW[rV * 64 + ((c ^ (rV & 7)) * 8)];
      f16x8 aQ = *(const f16x8*)&sX[rK * 64 + ((c ^ (rK & 7)) * 8)];
#pragma unroll
      for (int j = 0; j < 4; ++j) {
        const int rX = j * 16 + l15;
        const int rWq = 128 + j * 16 + l15;
        f16x8 bx = *(const f16x8*)&sX[rX * 64 + ((c ^ (rX & 7)) * 8)];
        f16x8 bw = *(const f16x8*)&sW[rWq * 64 + ((c ^ (rWq & 7)) * 8)];
        accK[j] = MFMA16(aK, bx, accK[j]);
        accV[j] = MFMA16(aV, bx, accV[j]);
        accQ[j] = MFMA16(aQ, bw, accQ[j]);
      }
    }
    __syncthreads();
  }
  const int b = m0 >> 12, t0 = m0 & 4095;
#pragma unroll
  for (int j = 0; j < 4; ++j) {
    const int h = j * 16 + l15;
    const float bqv = bq[h];
#pragma unroll
    for (int r = 0; r < 4; ++r) {
      const int m = m0 + wave * 16 + (lane >> 4) * 4 + r;
      const float v = accQ[j][r] + bqv;
      sigQ[(size_t)m * 64 + h] = (f16)(1.f / (1.f + expf(-v)));
    }
  }
  // ---- eK / eKV -> LDS transpose tile sT[128 h'][72 t-pad] ----
  f16* sT = sW;  // 9216 f16 <= 12288
#pragma unroll
  for (int r = 0; r < 4; ++r) {
    const int h = wave * 16 + (lane >> 4) * 4 + r;
    const float bkv = bk[h], bvv = bv[h];
#pragma unroll
    for (int j = 0; j < 4; ++j) {
      const int tl = j * 16 + l15;
      const float ek = expf(accK[j][r] + bkv);
      const float ev = accV[j][r] + bvv;
      sT[h * 72 + tl] = (f16)(ek * ev);
      sT[(64 + h) * 72 + tl] = (f16)ek;
    }
  }
  __syncthreads();
  // ---- emit fragment-order XT2, coalesced ----
  const int cb = wave;  // 0..3
  const int l31 = lane & 31;
  const int khalf = (lane >> 5) * 8;
#pragma unroll
  for (int cl = 0; cl < 4; ++cl) {
    f16x8 v = *(const f16x8*)&sT[(cb * 32 + l31) * 72 + cl * 16 + khalf];
    *(f16x8*)(XT2 + ((((size_t)b * 4 + cb) * 256 + (t0 >> 4) + cl) * 64 + lane) * 8) = v;
  }
}

// ---------------- k2_big: out = (sigQ*(ew@num^T)/(ew@den^T)) @ wp^T + bp ------------
// ZERO-STAGING GEMM: all operands pre-swizzled to MFMA-fragment order, so every
// fragment load is one coalesced global_load_dwordx4 (1 KB/wave-instr). No LDS,
// no barriers in the K-loop (compiler pipelines; 4 blocks/CU overlap). 256 thr,
// 4 waves, wave = 64 rows x (32 num + 32 den); acc[2][2] f32x16. ONE barrier
// total (LDS handoff of Yt to the fused out-projection tail, wp frags from L2).
// XCD map: bid&7 = XCD -> 4 m-tiles/XCD -> A panel 4 MB = L2-exact, read 8x.
__global__ __launch_bounds__(256, 4) void k2_big(const f16* __restrict__ eww,
                                                 const f16* __restrict__ XT2,
                                                 const f16* __restrict__ sigQ,
                                                 const f16* __restrict__ wpf,
                                                 const float* __restrict__ bp,
                                                 float* __restrict__ out) {
  __shared__ alignas(16) f16 sYt[128 * 72];
  const int tid = threadIdx.x;
  const int w = tid >> 6, lane = tid & 63;
  const int l31 = lane & 31, lhi = lane >> 5;
  const int bid = blockIdx.x;
  const int mt = (bid & 7) * 4 + (bid >> 6);  // XCD-hot A panel
  const int b = (bid >> 3) & 7;
  const int m0 = mt * 128;

  const f16* pa0 = eww + ((size_t)(mt * 4 + (w >> 1) * 2) * 256 * 64 + lane) * 8;
  const f16* pa1 = pa0 + (size_t)256 * 512;
  const int cbn = w & 1;
  const f16* pbn = XT2 + ((size_t)(b * 4 + cbn) * 256 * 64 + lane) * 8;
  const f16* pbd = XT2 + ((size_t)(b * 4 + 2 + cbn) * 256 * 64 + lane) * 8;

  f32x16 acc[2][2];
#pragma unroll
  for (int i = 0; i < 2; ++i)
#pragma unroll
    for (int j = 0; j < 2; ++j)
#pragma unroll
      for (int r = 0; r < 16; ++r) acc[i][j][r] = 0.f;

#pragma unroll 4
  for (int c = 0; c < 256; ++c) {
    f16x8 a0 = *(const f16x8*)(pa0 + (size_t)c * 512);
    f16x8 a1 = *(const f16x8*)(pa1 + (size_t)c * 512);
    f16x8 bn = *(const f16x8*)(pbn + (size_t)c * 512);
    f16x8 bd = *(const f16x8*)(pbd + (size_t)c * 512);
    acc[0][0] = MFMA32(a0, bn, acc[0][0]);
    acc[0][1] = MFMA32(a0, bd, acc[0][1]);
    acc[1][0] = MFMA32(a1, bn, acc[1][0]);
    acc[1][1] = MFMA32(a1, bd, acc[1][1]);
  }

  // ---- Yt = sigQ * num / den -> LDS ----
  const int wm = (w >> 1) * 64;
  const int hcol = cbn * 32 + l31;
#pragma unroll
  for (int i = 0; i < 2; ++i) {
#pragma unroll
    for (int r = 0; r < 16; ++r) {
      const int row = wm + i * 32 + (r & 3) + 8 * (r >> 2) + 4 * lhi;
      const float sq = (float)sigQ[((size_t)b * 4096 + m0 + row) * 64 + hcol];
      sYt[row * 72 + hcol] = (f16)(sq * acc[i][0][r] / acc[i][1][r]);
    }
  }
  __syncthreads();  // the only barrier in this kernel

  // ---- fused out-projection: rows w*32..+32, all 512 cols, wp frags from L2 ----
  f16x8 ay[4];
#pragma unroll
  for (int c = 0; c < 4; ++c)
    ay[c] = *(const f16x8*)&sYt[(w * 32 + l31) * 72 + c * 16 + lhi * 8];
#pragma unroll
  for (int cbo = 0; cbo < 16; ++cbo) {
    f32x16 oacc;
#pragma unroll
    for (int r = 0; r < 16; ++r) oacc[r] = 0.f;
#pragma unroll
    for (int c = 0; c < 4; ++c) {
      f16x8 bw = *(const f16x8*)(wpf + (((size_t)cbo * 4 + c) * 64 + lane) * 8);
      oacc = MFMA32(ay[c], bw, oacc);
    }
    const int od = cbo * 32 + l31;
    const float bpv = bp[od];
#pragma unroll
    for (int r = 0; r < 16; ++r) {
      const int orow = w * 32 + (r & 3) + 8 * (r >> 2) + 4 * lhi;
      out[((size_t)(b * 4096 + m0 + orow)) * 512 + od] = oacc[r] + bpv;
    }
  }
}

extern "C" void kernel_launch(void* const* d_in, const int* in_sizes, int n_in,
                              void* d_out, int out_size, void* d_ws, size_t ws_size,
                              hipStream_t stream) {
  const float* x = (const float*)d_in[0];
  const float* wq = (const float*)d_in[1];
  const float* bq = (const float*)d_in[2];
  const float* wk = (const float*)d_in[3];
  const float* bk = (const float*)d_in[4];
  const float* wv = (const float*)d_in[5];
  const float* bv = (const float*)d_in[6];
  const float* wp = (const float*)d_in[7];
  const float* bp = (const float*)d_in[8];
  const float* wbias = (const float*)d_in[9];
  float* out = (float*)d_out;

  char* ws = (char*)d_ws;
  f16* eww = (f16*)(ws);                 // 33,554,432 B (fragment-order exp(wbias))
  f16* XT2 = (f16*)(ws + 33554432);      //  8,388,608 B (fragment-order eKV/eK)
  f16* sigQ = (f16*)(ws + 41943040);     //  4,194,304 B
  f16* wqkvb = (f16*)(ws + 46137344);    //    196,608 B
  f16* wpf = (f16*)(ws + 46333952);      //     65,536 B (end 46,399,488)

  prep_eww<<<2048, 256, 0, stream>>>(wbias, eww, wq, wk, wv, wp, wqkvb, wpf);
  k1_qkv<<<512, 256, 0, stream>>>(x, wqkvb, bq, bk, bv, sigQ, XT2);
  k2_big<<<256, 256, 0, stream>>>(eww, XT2, sigQ, wpf, bp, out);
}

// Round 13
// 108.576 us; speedup vs baseline: 1.3136x; 1.3136x over previous
//
#include <hip/hip_runtime.h>
#include <math.h>

typedef _Float16 f16;
typedef __attribute__((ext_vector_type(8))) _Float16 f16x8;
typedef __attribute__((ext_vector_type(4))) _Float16 f16x4;
typedef __attribute__((ext_vector_type(4))) float f32x4;
typedef __attribute__((ext_vector_type(16))) float f32x16;

#define MFMA16(a, b, c) __builtin_amdgcn_mfma_f32_16x16x32_f16((a), (b), (c), 0, 0, 0)
#define MFMA32(a, b, c) __builtin_amdgcn_mfma_f32_32x32x16_f16((a), (b), (c), 0, 0, 0)

__device__ __forceinline__ void gld16(const f16* g, f16* l) {
  __builtin_amdgcn_global_load_lds(
      (const __attribute__((address_space(1))) unsigned int*)g,
      (__attribute__((address_space(3))) unsigned int*)l, 16, 0, 0);
}

__device__ __forceinline__ f16x8 pack8(const float* src) {
  float4 f0 = *(const float4*)src;
  float4 f1 = *(const float4*)(src + 4);
  f16x8 v;
  v[0] = (f16)f0.x; v[1] = (f16)f0.y; v[2] = (f16)f0.z; v[3] = (f16)f0.w;
  v[4] = (f16)f1.x; v[5] = (f16)f1.y; v[6] = (f16)f1.z; v[7] = (f16)f1.w;
  return v;
}

// ---------------- prep: ew = exp(wbias) f16 row-major; weights; wpf fragment-order ----
__global__ __launch_bounds__(256) void prep_ewpw(const float* __restrict__ wb,
                                                 f16* __restrict__ ew,
                                                 const float* __restrict__ wq,
                                                 const float* __restrict__ wk,
                                                 const float* __restrict__ wv,
                                                 const float* __restrict__ wp,
                                                 f16* __restrict__ wqkvb,
                                                 f16* __restrict__ wpf) {
  const size_t stride = (size_t)gridDim.x * 256;
  const size_t total = (size_t)4096 * 4096 / 4;
  for (size_t i = (size_t)blockIdx.x * 256 + threadIdx.x; i < total; i += stride) {
    float4 f = ((const float4*)wb)[i];
    f16x4 o;
    o.x = (f16)expf(f.x); o.y = (f16)expf(f.y);
    o.z = (f16)expf(f.z); o.w = (f16)expf(f.w);
    ((f16x4*)ew)[i] = o;
  }
  if (blockIdx.x < 128) {
    int i = blockIdx.x * 256 + threadIdx.x;  // [0, 32768)
    wqkvb[i] = (f16)wk[i];
    wqkvb[32768 + i] = (f16)wv[i];
    wqkvb[65536 + i] = (f16)wq[i];
  }
  if (blockIdx.x == 128) {
    const int tid = threadIdx.x;
#pragma unroll
    for (int u = 0; u < 16; ++u) {
      int d = u * 256 + tid;  // (dcb*4 + c)*64 + l
      int dcb = d >> 8, c = (d >> 6) & 3, l = d & 63;
      const float* src = wp + (size_t)(dcb * 32 + (l & 31)) * 64 + c * 16 + (l >> 5) * 8;
      f16x8 o;
#pragma unroll
      for (int e = 0; e < 8; ++e) o[e] = (f16)src[e];
      *(f16x8*)(wpf + ((size_t)d << 3)) = o;
    }
  }
}

// ---------------- k1_qkv: sigQ[m][h], XT[b*128+h][t]=eK*V, XT[b*128+64+h][t]=eK --------
__global__ __launch_bounds__(256) void k1_qkv(const float* __restrict__ x,
                                              const f16* __restrict__ wqkvb,
                                              const float* __restrict__ bq,
                                              const float* __restrict__ bk,
                                              const float* __restrict__ bv,
                                              f16* __restrict__ sigQ,
                                              f16* __restrict__ XT) {
  __shared__ alignas(16) f16 sW[192 * 64];
  __shared__ alignas(16) f16 sX[64 * 64];
  const int tid = threadIdx.x;
  const int wave = tid >> 6, lane = tid & 63;
  const int m0 = blockIdx.x * 64;
  const int l15 = lane & 15;

  f32x4 accQ[4], accK[4], accV[4];
#pragma unroll
  for (int j = 0; j < 4; ++j) {
    accQ[j] = (f32x4){0.f, 0.f, 0.f, 0.f};
    accK[j] = (f32x4){0.f, 0.f, 0.f, 0.f};
    accV[j] = (f32x4){0.f, 0.f, 0.f, 0.f};
  }

  const int sc8 = tid & 7;
  const int wr8 = (tid >> 3) & 7;
  const int wcol = (sc8 ^ wr8) * 8;

  for (int ks = 0; ks < 512; ks += 64) {
#pragma unroll
    for (int q = 0; q < 6; ++q) {
      int r = q * 32 + (tid >> 3);
      gld16(wqkvb + (size_t)r * 512 + ks + wcol, &sW[r * 64 + sc8 * 8]);
    }
#pragma unroll
    for (int u = 0; u < 2; ++u) {
      int un = tid + u * 256;
      int r = un >> 3, c8 = un & 7;
      *(f16x8*)&sX[r * 64 + ((c8 ^ (r & 7)) * 8)] =
          pack8(x + (size_t)(m0 + r) * 512 + ks + c8 * 8);
    }
    __syncthreads();
#pragma unroll
    for (int kk = 0; kk < 2; ++kk) {
      const int c = kk * 4 + (lane >> 4);
      const int rK = wave * 16 + l15;
      const int rV = 64 + rK;
      f16x8 aK = *(const f16x8*)&sW[rK * 64 + ((c ^ (rK & 7)) * 8)];
      f16x8 aV = *(const f16x8*)&sW[rV * 64 + ((c ^ (rV & 7)) * 8)];
      f16x8 aQ = *(const f16x8*)&sX[rK * 64 + ((c ^ (rK & 7)) * 8)];
#pragma unroll
      for (int j = 0; j < 4; ++j) {
        const int rX = j * 16 + l15;
        const int rWq = 128 + j * 16 + l15;
        f16x8 bx = *(const f16x8*)&sX[rX * 64 + ((c ^ (rX & 7)) * 8)];
        f16x8 bw = *(const f16x8*)&sW[rWq * 64 + ((c ^ (rWq & 7)) * 8)];
        accK[j] = MFMA16(aK, bx, accK[j]);
        accV[j] = MFMA16(aV, bx, accV[j]);
        accQ[j] = MFMA16(aQ, bw, accQ[j]);
      }
    }
    __syncthreads();
  }
  const int b = m0 >> 12, t0 = m0 & 4095;
#pragma unroll
  for (int j = 0; j < 4; ++j) {
    const int h = j * 16 + l15;
    const float bqv = bq[h];
#pragma unroll
    for (int r = 0; r < 4; ++r) {
      const int m = m0 + wave * 16 + (lane >> 4) * 4 + r;
      const float v = accQ[j][r] + bqv;
      sigQ[(size_t)m * 64 + h] = (f16)(1.f / (1.f + expf(-v)));
    }
  }
#pragma unroll
  for (int r = 0; r < 4; ++r) {
    const int h = wave * 16 + (lane >> 4) * 4 + r;
    const float bkv = bk[h], bvv = bv[h];
    const size_t rowKV = (size_t)(b * 128 + h) * 4096;
    const size_t rowK = (size_t)(b * 128 + 64 + h) * 4096;
#pragma unroll
    for (int j = 0; j < 4; ++j) {
      const int t = t0 + j * 16 + l15;
      const float ek = expf(accK[j][r] + bkv);
      const float ev = accV[j][r] + bvv;
      XT[rowKV + t] = (f16)(ek * ev);
      XT[rowK + t] = (f16)ek;
    }
  }
}

// ---------------- k2_main: partial num/den GEMM, K-split S=2 across blocks ----------
// grid 512 = (32 mt x 8 b x 2 kh) -> 2 blocks/CU (R7's proven 21.8 B/cyc regime).
// 256 thr, 4 waves; wave (wr=w>>1, wc=w&1): 64 rows x (32 num + 32 den cols).
// BK=64, dbuf LDS 64 KB, [64][128]-packed XOR-16 swizzle both-sides (R7-verbatim),
// counted vmcnt(8) 2-phase schedule (R7-verbatim). Partials -> f16, per-block
// contiguous 32 KB tile: P[kh*4194304 + (mt*8+b)*16384 + row*128 + col].
__global__ __launch_bounds__(256) void k2_main(const f16* __restrict__ A,
                                               const f16* __restrict__ Bm,
                                               f16* __restrict__ P) {
  __shared__ alignas(16) f16 smem[2][2][8192];  // [buf][A=0/B=1][64*128]
  const int tid = threadIdx.x;
  const int w = tid >> 6, lane = tid & 63;
  const int wr = w >> 1, wc = w & 1;
  const int bid = blockIdx.x;
  const int x = bid & 7, y = bid >> 3;          // x = XCD
  const int mt = x * 4 + (y >> 4);              // same-mt blocks share XCD
  const int rem = y & 15;
  const int b = rem >> 1, kh = rem & 1;
  const int m0 = mt * 128;
  const size_t k0 = (size_t)kh * 2048;
  const f16* Ab = A + (size_t)m0 * 4096 + k0;
  const f16* Bb = Bm + (size_t)(b * 128) * 4096 + k0;

  // staging map (R7's B-map verbatim): d = u*256+tid in [0,1024)
  int sRow[4], sCol[4];
#pragma unroll
  for (int u = 0; u < 4; ++u) {
    int d = u * 256 + tid;
    int p = d >> 4, c16 = d & 15;
    int oc = c16 ^ (p & 15);
    sRow[u] = p + 64 * (oc >> 3);
    sCol[u] = (oc & 7) * 8;
  }

  f32x16 accN[2], accD[2];
#pragma unroll
  for (int i = 0; i < 2; ++i)
#pragma unroll
    for (int r = 0; r < 16; ++r) { accN[i][r] = 0.f; accD[i][r] = 0.f; }

#define SB0 __builtin_amdgcn_sched_barrier(0)
#define K2_STAGE(buf, ks)                                                       \
  do {                                                                          \
    _Pragma("unroll") for (int u = 0; u < 4; ++u)                               \
        gld16(Ab + (size_t)sRow[u] * 4096 + (ks) + sCol[u],                     \
              &smem[buf][0][(u * 256 + tid) * 8]);                              \
    _Pragma("unroll") for (int u = 0; u < 4; ++u)                               \
        gld16(Bb + (size_t)sRow[u] * 4096 + (ks) + sCol[u],                     \
              &smem[buf][1][(u * 256 + tid) * 8]);                              \
  } while (0)

  K2_STAGE(0, 0);
  K2_STAGE(1, 64);
  asm volatile("s_waitcnt vmcnt(8)" ::: "memory");  // tile 0's 8 loads landed
  SB0;
  __builtin_amdgcn_s_barrier();
  SB0;

  const int l31 = lane & 31, l15 = lane & 15, lhi = lane >> 5;
  const int nk = 32;
  for (int t = 0; t < nk; ++t) {
    const int cur = t & 1;
    const f16* pA = smem[cur][0];
    const f16* pB = smem[cur][1];
    __builtin_amdgcn_s_setprio(1);
#pragma unroll
    for (int ks4 = 0; ks4 < 4; ++ks4) {
      const int kcc = ks4 * 2 + lhi;
      f16x8 a0 = *(const f16x8*)&pA[(l31)*128 + (((wr * 8 + kcc) ^ l15) * 8)];
      f16x8 a1 = *(const f16x8*)&pA[(32 + l31) * 128 + (((wr * 8 + kcc) ^ l15) * 8)];
      f16x8 bn = *(const f16x8*)&pB[(wc * 32 + l31) * 128 + ((kcc ^ l15) * 8)];
      f16x8 bd = *(const f16x8*)&pB[(wc * 32 + l31) * 128 + (((8 + kcc) ^ l15) * 8)];
      accN[0] = MFMA32(a0, bn, accN[0]);
      accD[0] = MFMA32(a0, bd, accD[0]);
      accN[1] = MFMA32(a1, bn, accN[1]);
      accD[1] = MFMA32(a1, bd, accD[1]);
    }
    __builtin_amdgcn_s_setprio(0);
    asm volatile("s_waitcnt lgkmcnt(0)" ::: "memory");
    SB0;
    __builtin_amdgcn_s_barrier();  // all waves done reading buf cur
    SB0;
    if (t + 2 < nk) {
      K2_STAGE(cur, (t + 2) * 64);
      asm volatile("s_waitcnt vmcnt(8)" ::: "memory");  // tile t+1 landed
    } else {
      asm volatile("s_waitcnt vmcnt(0)" ::: "memory");
    }
    SB0;
    __builtin_amdgcn_s_barrier();  // tile t+1 ready
    SB0;
  }
#undef K2_STAGE
#undef SB0

  // f16 partial write, per-block contiguous tile
  f16* Pp = P + (size_t)kh * 4194304 + (size_t)(mt * 8 + b) * 16384;
#pragma unroll
  for (int i = 0; i < 2; ++i) {
#pragma unroll
    for (int r = 0; r < 16; ++r) {
      const int crow = wr * 64 + i * 32 + (r & 3) + 8 * (r >> 2) + 4 * lhi;
      Pp[crow * 128 + wc * 32 + l31] = (f16)accN[i][r];
      Pp[crow * 128 + 64 + wc * 32 + l31] = (f16)accD[i][r];
    }
  }
}

// ---------------- k2_red: sum partials, Yt = sigQ*num/den, fused out-projection -------
// grid 256 = (mt, b), XCD-matched to k2_main's producer. Tail = R12-verified
// out-projection (wpf fragment-order, sYt [128][72]).
__global__ __launch_bounds__(256) void k2_red(const f16* __restrict__ P,
                                              const f16* __restrict__ sigQ,
                                              const f16* __restrict__ wpf,
                                              const float* __restrict__ bp,
                                              float* __restrict__ out) {
  __shared__ alignas(16) f16 sYt[128 * 72];
  const int tid = threadIdx.x;
  const int rid = blockIdx.x;
  const int mt = (rid & 7) * 4 + ((rid >> 3) & 3);  // same XCD as producer
  const int b = rid >> 5;
  const int m0 = mt * 128;
  const f16* P0 = P + (size_t)(mt * 8 + b) * 16384;
  const f16* P1 = P0 + 4194304;

#pragma unroll
  for (int u = 0; u < 4; ++u) {
    const int e = u * 256 + tid;  // [0,1024): row = e>>3, col-chunk c = e&7
    const int row = e >> 3, c = e & 7;
    f16x8 n0 = *(const f16x8*)(P0 + row * 128 + c * 8);
    f16x8 n1 = *(const f16x8*)(P1 + row * 128 + c * 8);
    f16x8 d0 = *(const f16x8*)(P0 + row * 128 + 64 + c * 8);
    f16x8 d1 = *(const f16x8*)(P1 + row * 128 + 64 + c * 8);
    f16x8 sq = *(const f16x8*)(sigQ + ((size_t)b * 4096 + m0 + row) * 64 + c * 8);
    f16x8 yv;
#pragma unroll
    for (int e8 = 0; e8 < 8; ++e8) {
      const float num = (float)n0[e8] + (float)n1[e8];
      const float den = (float)d0[e8] + (float)d1[e8];
      yv[e8] = (f16)((float)sq[e8] * num / den);
    }
    *(f16x8*)&sYt[row * 72 + c * 8] = yv;
  }
  __syncthreads();

  // R12-verified fused out-projection tail (256 thr, 4 waves)
  const int w = tid >> 6, lane = tid & 63;
  const int l31 = lane & 31, lhi = lane >> 5;
  f16x8 ay[4];
#pragma unroll
  for (int c = 0; c < 4; ++c)
    ay[c] = *(const f16x8*)&sYt[(w * 32 + l31) * 72 + c * 16 + lhi * 8];
#pragma unroll
  for (int cbo = 0; cbo < 16; ++cbo) {
    f32x16 oacc;
#pragma unroll
    for (int r = 0; r < 16; ++r) oacc[r] = 0.f;
#pragma unroll
    for (int c = 0; c < 4; ++c) {
      f16x8 bw = *(const f16x8*)(wpf + (((size_t)cbo * 4 + c) * 64 + lane) * 8);
      oacc = MFMA32(ay[c], bw, oacc);
    }
    const int od = cbo * 32 + l31;
    const float bpv = bp[od];
#pragma unroll
    for (int r = 0; r < 16; ++r) {
      const int orow = w * 32 + (r & 3) + 8 * (r >> 2) + 4 * lhi;
      out[((size_t)(b * 4096 + m0 + orow)) * 512 + od] = oacc[r] + bpv;
    }
  }
}

extern "C" void kernel_launch(void* const* d_in, const int* in_sizes, int n_in,
                              void* d_out, int out_size, void* d_ws, size_t ws_size,
                              hipStream_t stream) {
  const float* x = (const float*)d_in[0];
  const float* wq = (const float*)d_in[1];
  const float* bq = (const float*)d_in[2];
  const float* wk = (const float*)d_in[3];
  const float* bk = (const float*)d_in[4];
  const float* wv = (const float*)d_in[5];
  const float* bv = (const float*)d_in[6];
  const float* wp = (const float*)d_in[7];
  const float* bp = (const float*)d_in[8];
  const float* wbias = (const float*)d_in[9];
  float* out = (float*)d_out;

  char* ws = (char*)d_ws;
  f16* ew = (f16*)(ws);                  // 33,554,432 B
  f16* XT = (f16*)(ws + 33554432);       //  8,388,608 B
  f16* sigQ = (f16*)(ws + 41943040);     //  4,194,304 B
  f16* P = (f16*)(ws + 46137344);        // 16,777,216 B (2 x 8MB f16 partials)
  f16* wqkvb = (f16*)(ws + 62914560);    //    196,608 B
  f16* wpf = (f16*)(ws + 63111168);      //     65,536 B (end 63,176,704)

  prep_ewpw<<<4096, 256, 0, stream>>>(wbias, ew, wq, wk, wv, wp, wqkvb, wpf);
  k1_qkv<<<512, 256, 0, stream>>>(x, wqkvb, bq, bk, bv, sigQ, XT);
  k2_main<<<512, 256, 0, stream>>>(ew, XT, P);
  k2_red<<<256, 256, 0, stream>>>(P, sigQ, wpf, bp, out);
}

// Round 14
// 100.441 us; speedup vs baseline: 1.4200x; 1.0810x over previous
//
#include <hip/hip_runtime.h>
#include <math.h>

typedef _Float16 f16;
typedef __attribute__((ext_vector_type(8))) _Float16 f16x8;
typedef __attribute__((ext_vector_type(4))) _Float16 f16x4;
typedef __attribute__((ext_vector_type(4))) float f32x4;
typedef __attribute__((ext_vector_type(16))) float f32x16;

#define MFMA16(a, b, c) __builtin_amdgcn_mfma_f32_16x16x32_f16((a), (b), (c), 0, 0, 0)
#define MFMA32(a, b, c) __builtin_amdgcn_mfma_f32_32x32x16_f16((a), (b), (c), 0, 0, 0)

__device__ __forceinline__ void gld16(const f16* g, f16* l) {
  __builtin_amdgcn_global_load_lds(
      (const __attribute__((address_space(1))) unsigned int*)g,
      (__attribute__((address_space(3))) unsigned int*)l, 16, 0, 0);
}

__device__ __forceinline__ f16x8 pack8(const float* src) {
  float4 f0 = *(const float4*)src;
  float4 f1 = *(const float4*)(src + 4);
  f16x8 v;
  v[0] = (f16)f0.x; v[1] = (f16)f0.y; v[2] = (f16)f0.z; v[3] = (f16)f0.w;
  v[4] = (f16)f1.x; v[5] = (f16)f1.y; v[6] = (f16)f1.z; v[7] = (f16)f1.w;
  return v;
}

// ---------------- k0: merged prep (ew, wpf) + k1 (sigQ, XT) ----------------
// bid < 512: k1 block (weights self-cast from f32 via pack8 -> no prep dep).
// bid >= 512: grid-stride exp(wbias) -> ew f16; block 512 also builds wpf
// (wp in MFMA-fragment order). Independent halves co-schedule on the CUs.
__global__ __launch_bounds__(256) void k0(const float* __restrict__ x,
                                          const float* __restrict__ wq,
                                          const float* __restrict__ wk,
                                          const float* __restrict__ wv,
                                          const float* __restrict__ wp,
                                          const float* __restrict__ bq,
                                          const float* __restrict__ bk,
                                          const float* __restrict__ bv,
                                          const float* __restrict__ wbias,
                                          f16* __restrict__ ew,
                                          f16* __restrict__ wpf,
                                          f16* __restrict__ sigQ,
                                          f16* __restrict__ XT) {
  __shared__ alignas(16) f16 sW[192 * 64];
  __shared__ alignas(16) f16 sX[64 * 64];
  const int tid = threadIdx.x;

  if (blockIdx.x >= 512) {
    // ---- prep branch: ew = exp(wbias) f16, grid-stride ----
    const int pb = blockIdx.x - 512;
    const size_t stride = (size_t)(gridDim.x - 512) * 256;
    const size_t total = (size_t)4096 * 4096 / 4;
    for (size_t i = (size_t)pb * 256 + tid; i < total; i += stride) {
      float4 f = ((const float4*)wbias)[i];
      f16x4 o;
      o.x = (f16)expf(f.x); o.y = (f16)expf(f.y);
      o.z = (f16)expf(f.z); o.w = (f16)expf(f.w);
      ((f16x4*)ew)[i] = o;
    }
    if (pb == 0) {
#pragma unroll
      for (int u = 0; u < 16; ++u) {
        int d = u * 256 + tid;  // (dcb*4 + c)*64 + l
        int dcb = d >> 8, c = (d >> 6) & 3, l = d & 63;
        const float* src = wp + (size_t)(dcb * 32 + (l & 31)) * 64 + c * 16 + (l >> 5) * 8;
        f16x8 o;
#pragma unroll
        for (int e = 0; e < 8; ++e) o[e] = (f16)src[e];
        *(f16x8*)(wpf + ((size_t)d << 3)) = o;
      }
    }
    return;
  }

  // ---- k1 branch: sigQ[m][h], XT[b*128+h][t]=eK*V, XT[b*128+64+h][t]=eK ----
  const int wave = tid >> 6, lane = tid & 63;
  const int m0 = blockIdx.x * 64;
  const int l15 = lane & 15;

  f32x4 accQ[4], accK[4], accV[4];
#pragma unroll
  for (int j = 0; j < 4; ++j) {
    accQ[j] = (f32x4){0.f, 0.f, 0.f, 0.f};
    accK[j] = (f32x4){0.f, 0.f, 0.f, 0.f};
    accV[j] = (f32x4){0.f, 0.f, 0.f, 0.f};
  }

  for (int ks = 0; ks < 512; ks += 64) {
    // stage weights [192][64] from f32 (wk rows 0-63, wv 64-127, wq 128-191),
    // swizzled dest (c8 ^ (r&7)) — same final layout as before
#pragma unroll
    for (int u = 0; u < 6; ++u) {
      int un = tid + u * 256;
      int r = un >> 3, c8 = un & 7;
      const float* src = (u < 2) ? (wk + (size_t)r * 512)
                                 : (u < 4) ? (wv + (size_t)(r - 64) * 512)
                                           : (wq + (size_t)(r - 128) * 512);
      *(f16x8*)&sW[r * 64 + ((c8 ^ (r & 7)) * 8)] = pack8(src + ks + c8 * 8);
    }
#pragma unroll
    for (int u = 0; u < 2; ++u) {
      int un = tid + u * 256;
      int r = un >> 3, c8 = un & 7;
      *(f16x8*)&sX[r * 64 + ((c8 ^ (r & 7)) * 8)] =
          pack8(x + (size_t)(m0 + r) * 512 + ks + c8 * 8);
    }
    __syncthreads();
#pragma unroll
    for (int kk = 0; kk < 2; ++kk) {
      const int c = kk * 4 + (lane >> 4);
      const int rK = wave * 16 + l15;
      const int rV = 64 + rK;
      f16x8 aK = *(const f16x8*)&sW[rK * 64 + ((c ^ (rK & 7)) * 8)];
      f16x8 aV = *(const f16x8*)&sW[rV * 64 + ((c ^ (rV & 7)) * 8)];
      f16x8 aQ = *(const f16x8*)&sX[rK * 64 + ((c ^ (rK & 7)) * 8)];
#pragma unroll
      for (int j = 0; j < 4; ++j) {
        const int rX = j * 16 + l15;
        const int rWq = 128 + j * 16 + l15;
        f16x8 bx = *(const f16x8*)&sX[rX * 64 + ((c ^ (rX & 7)) * 8)];
        f16x8 bw = *(const f16x8*)&sW[rWq * 64 + ((c ^ (rWq & 7)) * 8)];
        accK[j] = MFMA16(aK, bx, accK[j]);
        accV[j] = MFMA16(aV, bx, accV[j]);
        accQ[j] = MFMA16(aQ, bw, accQ[j]);
      }
    }
    __syncthreads();
  }
  const int b = m0 >> 12, t0 = m0 & 4095;
#pragma unroll
  for (int j = 0; j < 4; ++j) {
    const int h = j * 16 + l15;
    const float bqv = bq[h];
#pragma unroll
    for (int r = 0; r < 4; ++r) {
      const int m = m0 + wave * 16 + (lane >> 4) * 4 + r;
      const float v = accQ[j][r] + bqv;
      sigQ[(size_t)m * 64 + h] = (f16)(1.f / (1.f + expf(-v)));
    }
  }
#pragma unroll
  for (int r = 0; r < 4; ++r) {
    const int h = wave * 16 + (lane >> 4) * 4 + r;
    const float bkv = bk[h], bvv = bv[h];
    const size_t rowKV = (size_t)(b * 128 + h) * 4096;
    const size_t rowK = (size_t)(b * 128 + 64 + h) * 4096;
#pragma unroll
    for (int j = 0; j < 4; ++j) {
      const int t = t0 + j * 16 + l15;
      const float ek = expf(accK[j][r] + bkv);
      const float ev = accV[j][r] + bvv;
      XT[rowKV + t] = (f16)(ek * ev);
      XT[rowK + t] = (f16)ek;
    }
  }
}

// ---------------- k2_main: partial num/den GEMM, K-split S=2 across blocks ----------
// R13-verbatim (validated; 43 us, 21.3 B/cyc staging at 2 blocks/CU).
__global__ __launch_bounds__(256) void k2_main(const f16* __restrict__ A,
                                               const f16* __restrict__ Bm,
                                               f16* __restrict__ P) {
  __shared__ alignas(16) f16 smem[2][2][8192];  // [buf][A=0/B=1][64*128]
  const int tid = threadIdx.x;
  const int w = tid >> 6, lane = tid & 63;
  const int wr = w >> 1, wc = w & 1;
  const int bid = blockIdx.x;
  const int x = bid & 7, y = bid >> 3;          // x = XCD
  const int mt = x * 4 + (y >> 4);              // same-mt blocks share XCD
  const int rem = y & 15;
  const int b = rem >> 1, kh = rem & 1;
  const int m0 = mt * 128;
  const size_t k0 = (size_t)kh * 2048;
  const f16* Ab = A + (size_t)m0 * 4096 + k0;
  const f16* Bb = Bm + (size_t)(b * 128) * 4096 + k0;

  int sRow[4], sCol[4];
#pragma unroll
  for (int u = 0; u < 4; ++u) {
    int d = u * 256 + tid;
    int p = d >> 4, c16 = d & 15;
    int oc = c16 ^ (p & 15);
    sRow[u] = p + 64 * (oc >> 3);
    sCol[u] = (oc & 7) * 8;
  }

  f32x16 accN[2], accD[2];
#pragma unroll
  for (int i = 0; i < 2; ++i)
#pragma unroll
    for (int r = 0; r < 16; ++r) { accN[i][r] = 0.f; accD[i][r] = 0.f; }

#define SB0 __builtin_amdgcn_sched_barrier(0)
#define K2_STAGE(buf, ks)                                                       \
  do {                                                                          \
    _Pragma("unroll") for (int u = 0; u < 4; ++u)                               \
        gld16(Ab + (size_t)sRow[u] * 4096 + (ks) + sCol[u],                     \
              &smem[buf][0][(u * 256 + tid) * 8]);                              \
    _Pragma("unroll") for (int u = 0; u < 4; ++u)                               \
        gld16(Bb + (size_t)sRow[u] * 4096 + (ks) + sCol[u],                     \
              &smem[buf][1][(u * 256 + tid) * 8]);                              \
  } while (0)

  K2_STAGE(0, 0);
  K2_STAGE(1, 64);
  asm volatile("s_waitcnt vmcnt(8)" ::: "memory");
  SB0;
  __builtin_amdgcn_s_barrier();
  SB0;

  const int l31 = lane & 31, l15 = lane & 15, lhi = lane >> 5;
  const int nk = 32;
  for (int t = 0; t < nk; ++t) {
    const int cur = t & 1;
    const f16* pA = smem[cur][0];
    const f16* pB = smem[cur][1];
    __builtin_amdgcn_s_setprio(1);
#pragma unroll
    for (int ks4 = 0; ks4 < 4; ++ks4) {
      const int kcc = ks4 * 2 + lhi;
      f16x8 a0 = *(const f16x8*)&pA[(l31)*128 + (((wr * 8 + kcc) ^ l15) * 8)];
      f16x8 a1 = *(const f16x8*)&pA[(32 + l31) * 128 + (((wr * 8 + kcc) ^ l15) * 8)];
      f16x8 bn = *(const f16x8*)&pB[(wc * 32 + l31) * 128 + ((kcc ^ l15) * 8)];
      f16x8 bd = *(const f16x8*)&pB[(wc * 32 + l31) * 128 + (((8 + kcc) ^ l15) * 8)];
      accN[0] = MFMA32(a0, bn, accN[0]);
      accD[0] = MFMA32(a0, bd, accD[0]);
      accN[1] = MFMA32(a1, bn, accN[1]);
      accD[1] = MFMA32(a1, bd, accD[1]);
    }
    __builtin_amdgcn_s_setprio(0);
    asm volatile("s_waitcnt lgkmcnt(0)" ::: "memory");
    SB0;
    __builtin_amdgcn_s_barrier();
    SB0;
    if (t + 2 < nk) {
      K2_STAGE(cur, (t + 2) * 64);
      asm volatile("s_waitcnt vmcnt(8)" ::: "memory");
    } else {
      asm volatile("s_waitcnt vmcnt(0)" ::: "memory");
    }
    SB0;
    __builtin_amdgcn_s_barrier();
    SB0;
  }
#undef K2_STAGE
#undef SB0

  f16* Pp = P + (size_t)kh * 4194304 + (size_t)(mt * 8 + b) * 16384;
#pragma unroll
  for (int i = 0; i < 2; ++i) {
#pragma unroll
    for (int r = 0; r < 16; ++r) {
      const int crow = wr * 64 + i * 32 + (r & 3) + 8 * (r >> 2) + 4 * lhi;
      Pp[crow * 128 + wc * 32 + l31] = (f16)accN[i][r];
      Pp[crow * 128 + 64 + wc * 32 + l31] = (f16)accD[i][r];
    }
  }
}

// ---------------- k2_red: sum partials, Yt, fused out-projection ----------------
// grid 512 x 512 thr = 2 blocks/CU, 16 waves/CU (fixes the 1-wave/SIMD latency
// bind). Block = 64 rows of one (mt,b) tile: one-pass Yt build into LDS, then
// 8 waves x 2 cbo of the R12/R13-verified fragment-order out-projection.
// XCD map: rid&7 = mt>>2 matches the producer's P tile.
__global__ __launch_bounds__(512) void k2_red(const f16* __restrict__ P,
                                              const f16* __restrict__ sigQ,
                                              const f16* __restrict__ wpf,
                                              const float* __restrict__ bp,
                                              float* __restrict__ out) {
  __shared__ alignas(16) f16 sYt[64 * 72];
  const int tid = threadIdx.x;
  const int rid = blockIdx.x;
  const int xcd = rid & 7;
  const int q = rid >> 3;          // [0,64)
  const int mt = xcd * 4 + (q & 3);
  const int b = (q >> 2) & 7;
  const int rh = q >> 5;           // row half 0/1
  const int m0 = mt * 128;
  const f16* P0 = P + (size_t)(mt * 8 + b) * 16384 + rh * 64 * 128;
  const f16* P1 = P0 + 4194304;

  {  // one chunk per thread: row = tid>>3 (0..63), c = tid&7
    const int row = tid >> 3, c = tid & 7;
    f16x8 n0 = *(const f16x8*)(P0 + row * 128 + c * 8);
    f16x8 n1 = *(const f16x8*)(P1 + row * 128 + c * 8);
    f16x8 d0 = *(const f16x8*)(P0 + row * 128 + 64 + c * 8);
    f16x8 d1 = *(const f16x8*)(P1 + row * 128 + 64 + c * 8);
    f16x8 sq = *(const f16x8*)(sigQ + ((size_t)b * 4096 + m0 + rh * 64 + row) * 64 + c * 8);
    f16x8 yv;
#pragma unroll
    for (int e = 0; e < 8; ++e) {
      const float num = (float)n0[e] + (float)n1[e];
      const float den = (float)d0[e] + (float)d1[e];
      yv[e] = (f16)((float)sq[e] * num / den);
    }
    *(f16x8*)&sYt[row * 72 + c * 8] = yv;
  }
  __syncthreads();

  const int w = tid >> 6, lane = tid & 63;
  const int l31 = lane & 31, lhi = lane >> 5;
  f16x8 ay[2][4];
#pragma unroll
  for (int rg = 0; rg < 2; ++rg)
#pragma unroll
    for (int c = 0; c < 4; ++c)
      ay[rg][c] = *(const f16x8*)&sYt[(rg * 32 + l31) * 72 + c * 16 + lhi * 8];

#pragma unroll
  for (int c2 = 0; c2 < 2; ++c2) {
    const int cbo = w * 2 + c2;
    f32x16 oacc[2];
#pragma unroll
    for (int rg = 0; rg < 2; ++rg)
#pragma unroll
      for (int r = 0; r < 16; ++r) oacc[rg][r] = 0.f;
#pragma unroll
    for (int c = 0; c < 4; ++c) {
      f16x8 bw = *(const f16x8*)(wpf + (((size_t)cbo * 4 + c) * 64 + lane) * 8);
      oacc[0] = MFMA32(ay[0][c], bw, oacc[0]);
      oacc[1] = MFMA32(ay[1][c], bw, oacc[1]);
    }
    const int od = cbo * 32 + l31;
    const float bpv = bp[od];
#pragma unroll
    for (int rg = 0; rg < 2; ++rg) {
#pragma unroll
      for (int r = 0; r < 16; ++r) {
        const int orow = rh * 64 + rg * 32 + (r & 3) + 8 * (r >> 2) + 4 * lhi;
        out[((size_t)(b * 4096 + m0 + orow)) * 512 + od] = oacc[rg][r] + bpv;
      }
    }
  }
}

extern "C" void kernel_launch(void* const* d_in, const int* in_sizes, int n_in,
                              void* d_out, int out_size, void* d_ws, size_t ws_size,
                              hipStream_t stream) {
  const float* x = (const float*)d_in[0];
  const float* wq = (const float*)d_in[1];
  const float* bq = (const float*)d_in[2];
  const float* wk = (const float*)d_in[3];
  const float* bk = (const float*)d_in[4];
  const float* wv = (const float*)d_in[5];
  const float* bv = (const float*)d_in[6];
  const float* wp = (const float*)d_in[7];
  const float* bp = (const float*)d_in[8];
  const float* wbias = (const float*)d_in[9];
  float* out = (float*)d_out;

  char* ws = (char*)d_ws;
  f16* ew = (f16*)(ws);                  // 33,554,432 B
  f16* XT = (f16*)(ws + 33554432);       //  8,388,608 B
  f16* sigQ = (f16*)(ws + 41943040);     //  4,194,304 B
  f16* P = (f16*)(ws + 46137344);        // 16,777,216 B (2 x 8MB f16 partials)
  f16* wpf = (f16*)(ws + 62914560);      //     65,536 B (end 62,980,096)

  k0<<<2560, 256, 0, stream>>>(x, wq, wk, wv, wp, bq, bk, bv, wbias, ew, wpf, sigQ, XT);
  k2_main<<<512, 256, 0, stream>>>(ew, XT, P);
  k2_red<<<512, 512, 0, stream>>>(P, sigQ, wpf, bp, out);
}

// Round 15
// 96.178 us; speedup vs baseline: 1.4830x; 1.0443x over previous
//
#include <hip/hip_runtime.h>
#include <math.h>

typedef _Float16 f16;
typedef __attribute__((ext_vector_type(8))) _Float16 f16x8;
typedef __attribute__((ext_vector_type(4))) _Float16 f16x4;
typedef __attribute__((ext_vector_type(4))) float f32x4;
typedef __attribute__((ext_vector_type(16))) float f32x16;

#define MFMA16(a, b, c) __builtin_amdgcn_mfma_f32_16x16x32_f16((a), (b), (c), 0, 0, 0)
#define MFMA32(a, b, c) __builtin_amdgcn_mfma_f32_32x32x16_f16((a), (b), (c), 0, 0, 0)

__device__ __forceinline__ void gld16(const f16* g, f16* l) {
  __builtin_amdgcn_global_load_lds(
      (const __attribute__((address_space(1))) unsigned int*)g,
      (__attribute__((address_space(3))) unsigned int*)l, 16, 0, 0);
}

__device__ __forceinline__ f16x8 pack8(const float* src) {
  float4 f0 = *(const float4*)src;
  float4 f1 = *(const float4*)(src + 4);
  f16x8 v;
  v[0] = (f16)f0.x; v[1] = (f16)f0.y; v[2] = (f16)f0.z; v[3] = (f16)f0.w;
  v[4] = (f16)f1.x; v[5] = (f16)f1.y; v[6] = (f16)f1.z; v[7] = (f16)f1.w;
  return v;
}

// ---------------- prep: ew = exp(wbias) f16 row-major; weights; wpf fragment-order ----
// R13-verbatim (validated).
__global__ __launch_bounds__(256) void prep_ewpw(const float* __restrict__ wb,
                                                 f16* __restrict__ ew,
                                                 const float* __restrict__ wq,
                                                 const float* __restrict__ wk,
                                                 const float* __restrict__ wv,
                                                 const float* __restrict__ wp,
                                                 f16* __restrict__ wqkvb,
                                                 f16* __restrict__ wpf) {
  const size_t stride = (size_t)gridDim.x * 256;
  const size_t total = (size_t)4096 * 4096 / 4;
  for (size_t i = (size_t)blockIdx.x * 256 + threadIdx.x; i < total; i += stride) {
    float4 f = ((const float4*)wb)[i];
    f16x4 o;
    o.x = (f16)expf(f.x); o.y = (f16)expf(f.y);
    o.z = (f16)expf(f.z); o.w = (f16)expf(f.w);
    ((f16x4*)ew)[i] = o;
  }
  if (blockIdx.x < 128) {
    int i = blockIdx.x * 256 + threadIdx.x;  // [0, 32768)
    wqkvb[i] = (f16)wk[i];
    wqkvb[32768 + i] = (f16)wv[i];
    wqkvb[65536 + i] = (f16)wq[i];
  }
  if (blockIdx.x == 128) {
    const int tid = threadIdx.x;
#pragma unroll
    for (int u = 0; u < 16; ++u) {
      int d = u * 256 + tid;  // (dcb*4 + c)*64 + l
      int dcb = d >> 8, c = (d >> 6) & 3, l = d & 63;
      const float* src = wp + (size_t)(dcb * 32 + (l & 31)) * 64 + c * 16 + (l >> 5) * 8;
      f16x8 o;
#pragma unroll
      for (int e = 0; e < 8; ++e) o[e] = (f16)src[e];
      *(f16x8*)(wpf + ((size_t)d << 3)) = o;
    }
  }
}

// ---------------- k1_qkv: sigQ[m][h], XT[b*128+h][t]=eK*V, XT[b*128+64+h][t]=eK --------
// R13-verbatim (validated).
__global__ __launch_bounds__(256) void k1_qkv(const float* __restrict__ x,
                                              const f16* __restrict__ wqkvb,
                                              const float* __restrict__ bq,
                                              const float* __restrict__ bk,
                                              const float* __restrict__ bv,
                                              f16* __restrict__ sigQ,
                                              f16* __restrict__ XT) {
  __shared__ alignas(16) f16 sW[192 * 64];
  __shared__ alignas(16) f16 sX[64 * 64];
  const int tid = threadIdx.x;
  const int wave = tid >> 6, lane = tid & 63;
  const int m0 = blockIdx.x * 64;
  const int l15 = lane & 15;

  f32x4 accQ[4], accK[4], accV[4];
#pragma unroll
  for (int j = 0; j < 4; ++j) {
    accQ[j] = (f32x4){0.f, 0.f, 0.f, 0.f};
    accK[j] = (f32x4){0.f, 0.f, 0.f, 0.f};
    accV[j] = (f32x4){0.f, 0.f, 0.f, 0.f};
  }

  const int sc8 = tid & 7;
  const int wr8 = (tid >> 3) & 7;
  const int wcol = (sc8 ^ wr8) * 8;

  for (int ks = 0; ks < 512; ks += 64) {
#pragma unroll
    for (int q = 0; q < 6; ++q) {
      int r = q * 32 + (tid >> 3);
      gld16(wqkvb + (size_t)r * 512 + ks + wcol, &sW[r * 64 + sc8 * 8]);
    }
#pragma unroll
    for (int u = 0; u < 2; ++u) {
      int un = tid + u * 256;
      int r = un >> 3, c8 = un & 7;
      *(f16x8*)&sX[r * 64 + ((c8 ^ (r & 7)) * 8)] =
          pack8(x + (size_t)(m0 + r) * 512 + ks + c8 * 8);
    }
    __syncthreads();
#pragma unroll
    for (int kk = 0; kk < 2; ++kk) {
      const int c = kk * 4 + (lane >> 4);
      const int rK = wave * 16 + l15;
      const int rV = 64 + rK;
      f16x8 aK = *(const f16x8*)&sW[rK * 64 + ((c ^ (rK & 7)) * 8)];
      f16x8 aV = *(const f16x8*)&sW[rV * 64 + ((c ^ (rV & 7)) * 8)];
      f16x8 aQ = *(const f16x8*)&sX[rK * 64 + ((c ^ (rK & 7)) * 8)];
#pragma unroll
      for (int j = 0; j < 4; ++j) {
        const int rX = j * 16 + l15;
        const int rWq = 128 + j * 16 + l15;
        f16x8 bx = *(const f16x8*)&sX[rX * 64 + ((c ^ (rX & 7)) * 8)];
        f16x8 bw = *(const f16x8*)&sW[rWq * 64 + ((c ^ (rWq & 7)) * 8)];
        accK[j] = MFMA16(aK, bx, accK[j]);
        accV[j] = MFMA16(aV, bx, accV[j]);
        accQ[j] = MFMA16(aQ, bw, accQ[j]);
      }
    }
    __syncthreads();
  }
  const int b = m0 >> 12, t0 = m0 & 4095;
#pragma unroll
  for (int j = 0; j < 4; ++j) {
    const int h = j * 16 + l15;
    const float bqv = bq[h];
#pragma unroll
    for (int r = 0; r < 4; ++r) {
      const int m = m0 + wave * 16 + (lane >> 4) * 4 + r;
      const float v = accQ[j][r] + bqv;
      sigQ[(size_t)m * 64 + h] = (f16)(1.f / (1.f + expf(-v)));
    }
  }
#pragma unroll
  for (int r = 0; r < 4; ++r) {
    const int h = wave * 16 + (lane >> 4) * 4 + r;
    const float bkv = bk[h], bvv = bv[h];
    const size_t rowKV = (size_t)(b * 128 + h) * 4096;
    const size_t rowK = (size_t)(b * 128 + 64 + h) * 4096;
#pragma unroll
    for (int j = 0; j < 4; ++j) {
      const int t = t0 + j * 16 + l15;
      const float ek = expf(accK[j][r] + bkv);
      const float ev = accV[j][r] + bvv;
      XT[rowKV + t] = (f16)(ek * ev);
      XT[rowK + t] = (f16)ek;
    }
  }
}

// ---------------- k2_main: partial num/den GEMM, K-split S=2 across blocks ----------
// R13-verbatim (validated; 43 us, 21.3 B/cyc staging at 2 blocks/CU).
__global__ __launch_bounds__(256) void k2_main(const f16* __restrict__ A,
                                               const f16* __restrict__ Bm,
                                               f16* __restrict__ P) {
  __shared__ alignas(16) f16 smem[2][2][8192];  // [buf][A=0/B=1][64*128]
  const int tid = threadIdx.x;
  const int w = tid >> 6, lane = tid & 63;
  const int wr = w >> 1, wc = w & 1;
  const int bid = blockIdx.x;
  const int x = bid & 7, y = bid >> 3;          // x = XCD
  const int mt = x * 4 + (y >> 4);              // same-mt blocks share XCD
  const int rem = y & 15;
  const int b = rem >> 1, kh = rem & 1;
  const int m0 = mt * 128;
  const size_t k0 = (size_t)kh * 2048;
  const f16* Ab = A + (size_t)m0 * 4096 + k0;
  const f16* Bb = Bm + (size_t)(b * 128) * 4096 + k0;

  int sRow[4], sCol[4];
#pragma unroll
  for (int u = 0; u < 4; ++u) {
    int d = u * 256 + tid;
    int p = d >> 4, c16 = d & 15;
    int oc = c16 ^ (p & 15);
    sRow[u] = p + 64 * (oc >> 3);
    sCol[u] = (oc & 7) * 8;
  }

  f32x16 accN[2], accD[2];
#pragma unroll
  for (int i = 0; i < 2; ++i)
#pragma unroll
    for (int r = 0; r < 16; ++r) { accN[i][r] = 0.f; accD[i][r] = 0.f; }

#define SB0 __builtin_amdgcn_sched_barrier(0)
#define K2_STAGE(buf, ks)                                                       \
  do {                                                                          \
    _Pragma("unroll") for (int u = 0; u < 4; ++u)                               \
        gld16(Ab + (size_t)sRow[u] * 4096 + (ks) + sCol[u],                     \
              &smem[buf][0][(u * 256 + tid) * 8]);                              \
    _Pragma("unroll") for (int u = 0; u < 4; ++u)                               \
        gld16(Bb + (size_t)sRow[u] * 4096 + (ks) + sCol[u],                     \
              &smem[buf][1][(u * 256 + tid) * 8]);                              \
  } while (0)

  K2_STAGE(0, 0);
  K2_STAGE(1, 64);
  asm volatile("s_waitcnt vmcnt(8)" ::: "memory");
  SB0;
  __builtin_amdgcn_s_barrier();
  SB0;

  const int l31 = lane & 31, l15 = lane & 15, lhi = lane >> 5;
  const int nk = 32;
  for (int t = 0; t < nk; ++t) {
    const int cur = t & 1;
    const f16* pA = smem[cur][0];
    const f16* pB = smem[cur][1];
    __builtin_amdgcn_s_setprio(1);
#pragma unroll
    for (int ks4 = 0; ks4 < 4; ++ks4) {
      const int kcc = ks4 * 2 + lhi;
      f16x8 a0 = *(const f16x8*)&pA[(l31)*128 + (((wr * 8 + kcc) ^ l15) * 8)];
      f16x8 a1 = *(const f16x8*)&pA[(32 + l31) * 128 + (((wr * 8 + kcc) ^ l15) * 8)];
      f16x8 bn = *(const f16x8*)&pB[(wc * 32 + l31) * 128 + ((kcc ^ l15) * 8)];
      f16x8 bd = *(const f16x8*)&pB[(wc * 32 + l31) * 128 + (((8 + kcc) ^ l15) * 8)];
      accN[0] = MFMA32(a0, bn, accN[0]);
      accD[0] = MFMA32(a0, bd, accD[0]);
      accN[1] = MFMA32(a1, bn, accN[1]);
      accD[1] = MFMA32(a1, bd, accD[1]);
    }
    __builtin_amdgcn_s_setprio(0);
    asm volatile("s_waitcnt lgkmcnt(0)" ::: "memory");
    SB0;
    __builtin_amdgcn_s_barrier();
    SB0;
    if (t + 2 < nk) {
      K2_STAGE(cur, (t + 2) * 64);
      asm volatile("s_waitcnt vmcnt(8)" ::: "memory");
    } else {
      asm volatile("s_waitcnt vmcnt(0)" ::: "memory");
    }
    SB0;
    __builtin_amdgcn_s_barrier();
    SB0;
  }
#undef K2_STAGE
#undef SB0

  f16* Pp = P + (size_t)kh * 4194304 + (size_t)(mt * 8 + b) * 16384;
#pragma unroll
  for (int i = 0; i < 2; ++i) {
#pragma unroll
    for (int r = 0; r < 16; ++r) {
      const int crow = wr * 64 + i * 32 + (r & 3) + 8 * (r >> 2) + 4 * lhi;
      Pp[crow * 128 + wc * 32 + l31] = (f16)accN[i][r];
      Pp[crow * 128 + 64 + wc * 32 + l31] = (f16)accD[i][r];
    }
  }
}

// ---------------- k2_red: sum partials, Yt, fused out-projection ----------------
// R14-verbatim (validated): grid 512 x 512 thr = 2 blocks/CU, 16 waves/CU.
__global__ __launch_bounds__(512) void k2_red(const f16* __restrict__ P,
                                              const f16* __restrict__ sigQ,
                                              const f16* __restrict__ wpf,
                                              const float* __restrict__ bp,
                                              float* __restrict__ out) {
  __shared__ alignas(16) f16 sYt[64 * 72];
  const int tid = threadIdx.x;
  const int rid = blockIdx.x;
  const int xcd = rid & 7;
  const int q = rid >> 3;          // [0,64)
  const int mt = xcd * 4 + (q & 3);
  const int b = (q >> 2) & 7;
  const int rh = q >> 5;           // row half 0/1
  const int m0 = mt * 128;
  const f16* P0 = P + (size_t)(mt * 8 + b) * 16384 + rh * 64 * 128;
  const f16* P1 = P0 + 4194304;

  {  // one chunk per thread: row = tid>>3 (0..63), c = tid&7
    const int row = tid >> 3, c = tid & 7;
    f16x8 n0 = *(const f16x8*)(P0 + row * 128 + c * 8);
    f16x8 n1 = *(const f16x8*)(P1 + row * 128 + c * 8);
    f16x8 d0 = *(const f16x8*)(P0 + row * 128 + 64 + c * 8);
    f16x8 d1 = *(const f16x8*)(P1 + row * 128 + 64 + c * 8);
    f16x8 sq = *(const f16x8*)(sigQ + ((size_t)b * 4096 + m0 + rh * 64 + row) * 64 + c * 8);
    f16x8 yv;
#pragma unroll
    for (int e = 0; e < 8; ++e) {
      const float num = (float)n0[e] + (float)n1[e];
      const float den = (float)d0[e] + (float)d1[e];
      yv[e] = (f16)((float)sq[e] * num / den);
    }
    *(f16x8*)&sYt[row * 72 + c * 8] = yv;
  }
  __syncthreads();

  const int w = tid >> 6, lane = tid & 63;
  const int l31 = lane & 31, lhi = lane >> 5;
  f16x8 ay[2][4];
#pragma unroll
  for (int rg = 0; rg < 2; ++rg)
#pragma unroll
    for (int c = 0; c < 4; ++c)
      ay[rg][c] = *(const f16x8*)&sYt[(rg * 32 + l31) * 72 + c * 16 + lhi * 8];

#pragma unroll
  for (int c2 = 0; c2 < 2; ++c2) {
    const int cbo = w * 2 + c2;
    f32x16 oacc[2];
#pragma unroll
    for (int rg = 0; rg < 2; ++rg)
#pragma unroll
      for (int r = 0; r < 16; ++r) oacc[rg][r] = 0.f;
#pragma unroll
    for (int c = 0; c < 4; ++c) {
      f16x8 bw = *(const f16x8*)(wpf + (((size_t)cbo * 4 + c) * 64 + lane) * 8);
      oacc[0] = MFMA32(ay[0][c], bw, oacc[0]);
      oacc[1] = MFMA32(ay[1][c], bw, oacc[1]);
    }
    const int od = cbo * 32 + l31;
    const float bpv = bp[od];
#pragma unroll
    for (int rg = 0; rg < 2; ++rg) {
#pragma unroll
      for (int r = 0; r < 16; ++r) {
        const int orow = rh * 64 + rg * 32 + (r & 3) + 8 * (r >> 2) + 4 * lhi;
        out[((size_t)(b * 4096 + m0 + orow)) * 512 + od] = oacc[rg][r] + bpv;
      }
    }
  }
}

extern "C" void kernel_launch(void* const* d_in, const int* in_sizes, int n_in,
                              void* d_out, int out_size, void* d_ws, size_t ws_size,
                              hipStream_t stream) {
  const float* x = (const float*)d_in[0];
  const float* wq = (const float*)d_in[1];
  const float* bq = (const float*)d_in[2];
  const float* wk = (const float*)d_in[3];
  const float* bk = (const float*)d_in[4];
  const float* wv = (const float*)d_in[5];
  const float* bv = (const float*)d_in[6];
  const float* wp = (const float*)d_in[7];
  const float* bp = (const float*)d_in[8];
  const float* wbias = (const float*)d_in[9];
  float* out = (float*)d_out;

  char* ws = (char*)d_ws;
  f16* ew = (f16*)(ws);                  // 33,554,432 B
  f16* XT = (f16*)(ws + 33554432);       //  8,388,608 B
  f16* sigQ = (f16*)(ws + 41943040);     //  4,194,304 B
  f16* P = (f16*)(ws + 46137344);        // 16,777,216 B (2 x 8MB f16 partials)
  f16* wqkvb = (f16*)(ws + 62914560);    //    196,608 B
  f16* wpf = (f16*)(ws + 63111168);      //     65,536 B (end 63,176,704)

  prep_ewpw<<<4096, 256, 0, stream>>>(wbias, ew, wq, wk, wv, wp, wqkvb, wpf);
  k1_qkv<<<512, 256, 0, stream>>>(x, wqkvb, bq, bk, bv, sigQ, XT);
  k2_main<<<512, 256, 0, stream>>>(ew, XT, P);
  k2_red<<<512, 512, 0, stream>>>(P, sigQ, wpf, bp, out);
}